// Round 11
// baseline (180.921 us; speedup 1.0000x reference)
//
#include <hip/hip_runtime.h>
#include <hip/hip_bf16.h>

#define BB 2
#define NN 2048
#define CC 768
#define HH 12
#define DD 64
#define MM 4096
#define N3 2304

typedef __attribute__((ext_vector_type(8))) short bf16x8;
typedef __attribute__((ext_vector_type(4))) float f32x4;

// 0.125 (1/sqrt(D)) * log2(e) folded into Q so softmax runs in base-2 units
#define QSCALE 0.18033688011112043f

// Q/K/V fragment-contiguous permutation: within each 32-element k-block, the
// element at offset o is stored at position p(o) = ((o&15)>>2)*8 + (o>>4)*4 + (o&3).
// The MFMA A/B-fragment for lane-group lg is then 8 contiguous shorts at
// position lg*8 -> single 16B load (global or LDS).

__device__ __forceinline__ unsigned short f2bf(float f) {
    union { float f; unsigned u; } v; v.f = f;
    unsigned r = v.u + 0x7FFFu + ((v.u >> 16) & 1u);
    return (unsigned short)(r >> 16);
}

// RNE cast — compiler lowers pairs to v_cvt_pk_bf16_f32 (m240: don't hand-write)
__device__ __forceinline__ short f2bf_rn(float f) {
    union { __hip_bfloat16 h; short s; } v;
    v.h = __float2bfloat16(f);
    return v.s;
}

__device__ __forceinline__ float exp2_hw(float x) {
    float r;
    asm("v_exp_f32 %0, %1" : "=v"(r) : "v"(x));
    return r;
}

// loads elements [0..3] and [16..19] from p (bf16 A/B fragment k-pattern)
__device__ __forceinline__ bf16x8 ld_frag(const unsigned short* p) {
    bf16x8 r;
    __builtin_memcpy(&r, p, 8);
    __builtin_memcpy((char*)&r + 8, p + 16, 8);
    return r;
}

// contiguous 16B fragment load (permuted storage)
__device__ __forceinline__ bf16x8 ld_frag16(const unsigned short* p) {
    bf16x8 r;
    __builtin_memcpy(&r, p, 16);
    return r;
}

__global__ void k_cvt(const float* __restrict__ s, unsigned short* __restrict__ d, int n4) {
    int i = blockIdx.x * blockDim.x + threadIdx.x;
    int st = gridDim.x * blockDim.x;
    for (; i < n4; i += st) {
        float4 v = ((const float4*)s)[i];
        ushort4 o;
        o.x = f2bf(v.x); o.y = f2bf(v.y); o.z = f2bf(v.z); o.w = f2bf(v.w);
        ((ushort4*)d)[i] = o;
    }
}

// transpose+convert: src f32 [R][Cc] -> dst bf16 [Cc][R]; grid (Cc/64, R/64)
__global__ void k_cvtT(const float* __restrict__ s, unsigned short* __restrict__ d,
                       int R, int Cc) {
    __shared__ unsigned short t[64][72];
    const int c0 = blockIdx.x * 64, r0 = blockIdx.y * 64;
    const int tr = threadIdx.x >> 4;
    const int tc = (threadIdx.x & 15) * 4;
#pragma unroll
    for (int i = 0; i < 4; i++) {
        int r = tr + i * 16;
        float4 v = *(const float4*)(s + (size_t)(r0 + r) * Cc + c0 + tc);
        t[tc + 0][r] = f2bf(v.x);
        t[tc + 1][r] = f2bf(v.y);
        t[tc + 2][r] = f2bf(v.z);
        t[tc + 3][r] = f2bf(v.w);
    }
    __syncthreads();
    const int wr = threadIdx.x >> 2;
    const int wc = (threadIdx.x & 3) * 16;
    *(uint4*)(d + (size_t)(c0 + wr) * R + r0 + wc)     = *(uint4*)&t[wr][wc];
    *(uint4*)(d + (size_t)(c0 + wr) * R + r0 + wc + 8) = *(uint4*)&t[wr][wc + 8];
}

// ---------------- GEMM1: qkv = x @ W_qkv + b, fused RoPE ----------------
// grid (32, 36), block 256. Tile 128(M) x 64(N), BK=32. Wt is [N3][CC] (transposed).
// Q, K and V outputs all stored with the frag-contiguous 32-block permutation.
__launch_bounds__(256)
__global__ void k_qkv(const unsigned short* __restrict__ xb,
                      const unsigned short* __restrict__ wt,
                      const float* __restrict__ bias,
                      const float* __restrict__ sinp,
                      const float* __restrict__ cosp,
                      unsigned short* __restrict__ qws,
                      unsigned short* __restrict__ kws,
                      unsigned short* __restrict__ vws) {
    __shared__ unsigned short As[128][40];   // [m][k]
    __shared__ unsigned short Bs[64][40];    // [j][k]
    const int tid = threadIdx.x;
    const int lane = tid & 63, w = tid >> 6;
    const int ql = lane & 15, lg = lane >> 4;
    const int row0 = blockIdx.x * 128;
    const int j0 = blockIdx.y * 64;

    f32x4 acc[2][4];
#pragma unroll
    for (int a = 0; a < 2; a++)
#pragma unroll
        for (int b = 0; b < 4; b++) acc[a][b] = f32x4{0.f, 0.f, 0.f, 0.f};

    const int ar = tid >> 1, ac = (tid & 1) * 16;
    const int jr = tid >> 2, kc = (tid & 3) * 8;

    for (int k0 = 0; k0 < CC; k0 += 32) {
        uint4 av0 = *(const uint4*)(xb + (size_t)(row0 + ar) * CC + k0 + ac);
        uint4 av1 = *(const uint4*)(xb + (size_t)(row0 + ar) * CC + k0 + ac + 8);
        uint4 bv  = *(const uint4*)(wt + (size_t)(j0 + jr) * CC + k0 + kc);
        *(uint4*)&As[ar][ac]     = av0;
        *(uint4*)&As[ar][ac + 8] = av1;
        *(uint4*)&Bs[jr][kc]     = bv;
        __syncthreads();

        bf16x8 af[2], bfr[4];
#pragma unroll
        for (int fr = 0; fr < 2; fr++) af[fr] = ld_frag(&As[w * 32 + fr * 16 + ql][lg * 4]);
#pragma unroll
        for (int fn = 0; fn < 4; fn++) bfr[fn] = ld_frag(&Bs[fn * 16 + ql][lg * 4]);
#pragma unroll
        for (int fr = 0; fr < 2; fr++)
#pragma unroll
            for (int fn = 0; fn < 4; fn++)
                acc[fr][fn] = __builtin_amdgcn_mfma_f32_16x16x32_bf16(af[fr], bfr[fn], acc[fr][fn], 0, 0, 0);
        __syncthreads();
    }

    float vals[2][4][4];
#pragma unroll
    for (int fr = 0; fr < 2; fr++)
#pragma unroll
        for (int fn = 0; fn < 4; fn++) {
            float bj = bias[j0 + fn * 16 + ql];
#pragma unroll
            for (int r = 0; r < 4; r++) vals[fr][fn][r] = acc[fr][fn][r] + bj;
        }
    const int t = j0 / CC;
    const int h = (j0 % CC) >> 6;
    if (t < 2) {
        unsigned short* outp = (t == 0) ? qws : kws;
        const float qs = (t == 0) ? QSCALE : 1.0f;
#pragma unroll
        for (int fr = 0; fr < 2; fr++)
#pragma unroll
            for (int r = 0; r < 4; r++) {
                int m = row0 + w * 32 + fr * 16 + lg * 4 + r;
                int b = m >> 11, n = m & (NN - 1);
#pragma unroll
                for (int fn = 0; fn < 4; fn++) {
                    int d = fn * 16 + ql;
                    float cv = cosp[n * DD + d], sv = sinp[n * DD + d];
                    float other = vals[fr][fn ^ 2][r];  // partner at d +/- 32
                    float rv = (vals[fr][fn][r] * cv + ((fn < 2) ? -other : other) * sv) * qs;
                    // Q and K columns both permuted (frag-contiguous)
                    int dcol = (fn >> 1) * 32 + (ql >> 2) * 8 + (fn & 1) * 4 + (ql & 3);
                    outp[((size_t)(b * HH + h) * NN + n) * DD + dcol] = f2bf(rv);
                }
            }
    } else {
#pragma unroll
        for (int fr = 0; fr < 2; fr++)
#pragma unroll
            for (int r = 0; r < 4; r++) {
                int m = row0 + w * 32 + fr * 16 + lg * 4 + r;
                int b = m >> 11, n = m & (NN - 1);
                // V n-columns permuted within 32-blocks: (n&31) = (fr&1)*16+lg*4+r
                int ncol = (n & ~31) + lg * 8 + (fr & 1) * 4 + r;
#pragma unroll
                for (int fn = 0; fn < 4; fn++) {
                    int d = fn * 16 + ql;
                    vws[((size_t)(b * HH + h) * DD + d) * NN + ncol] = f2bf(vals[fr][fn][r]);
                }
            }
    }
}

// ---------------- Attention (flash, S^T / O^T, software-pipelined) ----------------
// grid 768 (1-D, XCD-swizzled), block 128 (2 waves). Wave owns 32 q; block 64 q.
// Pipeline: per iteration t, compute QK(t+1) (MFMA, from LDS K dbuf) THEN
// softmax(t) (VALU) in the same scheduling region — separate pipes overlap (m114)
// — then PV(t) from a 3-deep V buffer. One barrier per iteration.
__launch_bounds__(128)
__global__ void k_attn(const unsigned short* __restrict__ qws,
                       const unsigned short* __restrict__ kws,
                       const unsigned short* __restrict__ vws,
                       unsigned short* __restrict__ yws) {
    __shared__ unsigned short Ks[2][64][72];  // K(t) double buffer  [kk][d-perm]
    __shared__ unsigned short Vs[3][64][72];  // V(t) triple buffer  [d][kk-perm]
    const int tid = threadIdx.x;
    const int lane = tid & 63, w = tid >> 6;
    const int ql = lane & 15, lg = lane >> 4;
    const int d0 = blockIdx.x;
    const int bh = (d0 & 7) + 8 * (d0 >> 8);     // 0..23, 3 heads per XCD class
    const int qb = (d0 >> 3) & 31;               // 0..31
    const int qw = qb * 64 + w * 32;
    const unsigned short* Qp = qws + (size_t)bh * NN * DD;
    const unsigned short* Kp = kws + (size_t)bh * NN * DD;
    const unsigned short* Vp = vws + (size_t)bh * DD * NN;

    // Q fragments hoisted (B-operand of S^T): col q = ql, k = d (pre-scaled, permuted)
    bf16x8 qf[2][2];
#pragma unroll
    for (int fn = 0; fn < 2; fn++)
#pragma unroll
        for (int kb = 0; kb < 2; kb++)
            qf[fn][kb] = ld_frag16(Qp + (size_t)(qw + fn * 16 + ql) * DD + kb * 32 + lg * 8);

    f32x4 oacc[4][2];
#pragma unroll
    for (int a = 0; a < 4; a++)
#pragma unroll
        for (int b = 0; b < 2; b++) oacc[a][b] = f32x4{0.f, 0.f, 0.f, 0.f};
    float mrun[2] = {-1e30f, -1e30f}, lrun[2] = {0.f, 0.f};

    const int srow = tid >> 1;        // 0..63
    const int shalf = (tid & 1) * 32; // 32-short (one k-block) granularity

    // prologue: stage tile 0
#pragma unroll
    for (int j = 0; j < 4; j++) {
        *(uint4*)&Ks[0][srow][shalf + j * 8] = *(const uint4*)(Kp + (size_t)srow * DD + shalf + j * 8);
        *(uint4*)&Vs[0][srow][shalf + j * 8] = *(const uint4*)(Vp + (size_t)srow * NN + shalf + j * 8);
    }
    __syncthreads();

    // QK(0) -> sc
    f32x4 sc[4][2];
#pragma unroll
    for (int a = 0; a < 4; a++)
#pragma unroll
        for (int b = 0; b < 2; b++) sc[a][b] = f32x4{0.f, 0.f, 0.f, 0.f};
#pragma unroll
    for (int kb = 0; kb < 2; kb++) {
        bf16x8 kf[4];
#pragma unroll
        for (int fr = 0; fr < 4; fr++)
            kf[fr] = ld_frag16(&Ks[0][fr * 16 + ql][kb * 32 + lg * 8]);
#pragma unroll
        for (int fr = 0; fr < 4; fr++)
#pragma unroll
            for (int fn = 0; fn < 2; fn++)
                sc[fr][fn] = __builtin_amdgcn_mfma_f32_16x16x32_bf16(kf[fr], qf[fn][kb], sc[fr][fn], 0, 0, 0);
    }

    // stage tile 1
    {
        uint4 kn[4], vn[4];
#pragma unroll
        for (int j = 0; j < 4; j++) {
            kn[j] = *(const uint4*)(Kp + (size_t)(64 + srow) * DD + shalf + j * 8);
            vn[j] = *(const uint4*)(Vp + (size_t)srow * NN + 64 + shalf + j * 8);
        }
#pragma unroll
        for (int j = 0; j < 4; j++) {
            *(uint4*)&Ks[1][srow][shalf + j * 8] = kn[j];
            *(uint4*)&Vs[1][srow][shalf + j * 8] = vn[j];
        }
    }
    __syncthreads();

    const int NT = NN / 64;
    int vcur = 0;   // Vs buffer holding V(t)
    for (int t = 0; t < NT; t++) {
        const bool hasn1 = (t + 1 < NT);
        const bool hasn2 = (t + 2 < NT);
        uint4 kn[4], vn[4];
        if (hasn2) {
#pragma unroll
            for (int j = 0; j < 4; j++) {
                kn[j] = *(const uint4*)(Kp + (size_t)((t + 2) * 64 + srow) * DD + shalf + j * 8);
                vn[j] = *(const uint4*)(Vp + (size_t)srow * NN + (t + 2) * 64 + shalf + j * 8);
            }
        }

        // QK(t+1) -> sn (MFMA pipe; independent of softmax(t) below -> overlaps)
        f32x4 sn[4][2];
#pragma unroll
        for (int a = 0; a < 4; a++)
#pragma unroll
            for (int b = 0; b < 2; b++) sn[a][b] = f32x4{0.f, 0.f, 0.f, 0.f};
        if (hasn1) {
            const unsigned short (*Kc)[72] = Ks[(t + 1) & 1];
            __builtin_amdgcn_s_setprio(1);
#pragma unroll
            for (int kb = 0; kb < 2; kb++) {
                bf16x8 kf[4];
#pragma unroll
                for (int fr = 0; fr < 4; fr++)
                    kf[fr] = ld_frag16(&Kc[fr * 16 + ql][kb * 32 + lg * 8]);
#pragma unroll
                for (int fr = 0; fr < 4; fr++)
#pragma unroll
                    for (int fn = 0; fn < 2; fn++)
                        sn[fr][fn] = __builtin_amdgcn_mfma_f32_16x16x32_bf16(kf[fr], qf[fn][kb], sn[fr][fn], 0, 0, 0);
            }
            __builtin_amdgcn_s_setprio(0);
        }

        // softmax(t) on sc (VALU pipe)
        bf16x8 pB[2][2];
#pragma unroll
        for (int fn = 0; fn < 2; fn++) {
            float ma = fmaxf(fmaxf(sc[0][fn][0], sc[0][fn][1]), fmaxf(sc[0][fn][2], sc[0][fn][3]));
            float mb = fmaxf(fmaxf(sc[1][fn][0], sc[1][fn][1]), fmaxf(sc[1][fn][2], sc[1][fn][3]));
            float mc = fmaxf(fmaxf(sc[2][fn][0], sc[2][fn][1]), fmaxf(sc[2][fn][2], sc[2][fn][3]));
            float md = fmaxf(fmaxf(sc[3][fn][0], sc[3][fn][1]), fmaxf(sc[3][fn][2], sc[3][fn][3]));
            float tm = fmaxf(fmaxf(ma, mb), fmaxf(mc, md));
            tm = fmaxf(tm, __shfl_xor(tm, 16));
            tm = fmaxf(tm, __shfl_xor(tm, 32));
            // defer-max: rescale only when running max grows by more than 8 (log2) [T13]
            if (__any(tm > mrun[fn] + 8.0f)) {
                float mn = fmaxf(mrun[fn], tm);
                float scl = exp2_hw(mrun[fn] - mn);
                lrun[fn] *= scl;
#pragma unroll
                for (int db = 0; db < 4; db++) oacc[db][fn] *= scl;
                mrun[fn] = mn;
            }
            float ts = 0.f;
#pragma unroll
            for (int fr = 0; fr < 4; fr++)
#pragma unroll
                for (int r = 0; r < 4; r++) {
                    float p = exp2_hw(sc[fr][fn][r] - mrun[fn]);
                    sc[fr][fn][r] = p;
                    ts += p;
                }
            ts += __shfl_xor(ts, 16);
            ts += __shfl_xor(ts, 32);
            lrun[fn] += ts;

            // in-lane repack: S^T C/D frag -> B-operand frags of PV (RNE pk-cvt)
#pragma unroll
            for (int kkb = 0; kkb < 2; kkb++) {
                bf16x8 t8;
#pragma unroll
                for (int e = 0; e < 8; e++)
                    t8[e] = f2bf_rn(sc[kkb * 2 + (e >> 2)][fn][e & 3]);
                pB[fn][kkb] = t8;
            }
        }

        // PV(t): O^T[d][q] += sum_kk V^T[d][kk] P^T[kk][q]
        {
            const unsigned short (*Vc)[72] = Vs[vcur];
            __builtin_amdgcn_s_setprio(1);
#pragma unroll
            for (int db = 0; db < 4; db++) {
                bf16x8 va[2];
#pragma unroll
                for (int kkb = 0; kkb < 2; kkb++)
                    va[kkb] = ld_frag16(&Vc[db * 16 + ql][kkb * 32 + lg * 8]);
#pragma unroll
                for (int kkb = 0; kkb < 2; kkb++)
#pragma unroll
                    for (int fn = 0; fn < 2; fn++)
                        oacc[db][fn] = __builtin_amdgcn_mfma_f32_16x16x32_bf16(va[kkb], pB[fn][kkb], oacc[db][fn], 0, 0, 0);
            }
            __builtin_amdgcn_s_setprio(0);
        }

        if (hasn2) {
            // write tile t+2: K -> Ks[t&1] (holds dead K(t)), V -> Vs[(vcur+2)%3]
            int vw = vcur + 2; if (vw >= 3) vw -= 3;
#pragma unroll
            for (int j = 0; j < 4; j++) {
                *(uint4*)&Ks[t & 1][srow][shalf + j * 8] = kn[j];
                *(uint4*)&Vs[vw][srow][shalf + j * 8] = vn[j];
            }
        }
        if (hasn1) {
            __syncthreads();
#pragma unroll
            for (int a = 0; a < 4; a++)
#pragma unroll
                for (int b = 0; b < 2; b++) sc[a][b] = sn[a][b];
        }
        vcur++; if (vcur >= 3) vcur -= 3;
    }

    // epilogue: O^T frag row = d, col = q; vectorized 8B stores
    const int b = bh / HH, h = bh % HH;
#pragma unroll
    for (int fn = 0; fn < 2; fn++) {
        float inv = 1.0f / lrun[fn];
        int q = qw + fn * 16 + ql;
        unsigned short* yp = yws + (size_t)(b * NN + q) * CC + h * DD + lg * 4;
#pragma unroll
        for (int db = 0; db < 4; db++) {
            ushort4 o;
            o.x = f2bf(oacc[db][fn][0] * inv);
            o.y = f2bf(oacc[db][fn][1] * inv);
            o.z = f2bf(oacc[db][fn][2] * inv);
            o.w = f2bf(oacc[db][fn][3] * inv);
            *(ushort4*)(yp + db * 16) = o;
        }
    }
}

// ---------------- GEMM2: out = y @ W_out + b_out (f32 out) ----------------
// Wot is [CC][CC] transposed. grid (32,12), block 256, tile 128x64.
__launch_bounds__(256)
__global__ void k_out(const unsigned short* __restrict__ yb,
                      const unsigned short* __restrict__ wt,
                      const float* __restrict__ bias,
                      float* __restrict__ out) {
    __shared__ unsigned short As[128][40];
    __shared__ unsigned short Bs[64][40];
    const int tid = threadIdx.x;
    const int lane = tid & 63, w = tid >> 6;
    const int ql = lane & 15, lg = lane >> 4;
    const int row0 = blockIdx.x * 128;
    const int j0 = blockIdx.y * 64;

    f32x4 acc[2][4];
#pragma unroll
    for (int a = 0; a < 2; a++)
#pragma unroll
        for (int b = 0; b < 4; b++) acc[a][b] = f32x4{0.f, 0.f, 0.f, 0.f};

    const int ar = tid >> 1, ac = (tid & 1) * 16;
    const int jr = tid >> 2, kc = (tid & 3) * 8;

    for (int k0 = 0; k0 < CC; k0 += 32) {
        uint4 av0 = *(const uint4*)(yb + (size_t)(row0 + ar) * CC + k0 + ac);
        uint4 av1 = *(const uint4*)(yb + (size_t)(row0 + ar) * CC + k0 + ac + 8);
        uint4 bv  = *(const uint4*)(wt + (size_t)(j0 + jr) * CC + k0 + kc);
        *(uint4*)&As[ar][ac]     = av0;
        *(uint4*)&As[ar][ac + 8] = av1;
        *(uint4*)&Bs[jr][kc]     = bv;
        __syncthreads();

        bf16x8 af[2], bfr[4];
#pragma unroll
        for (int fr = 0; fr < 2; fr++) af[fr] = ld_frag(&As[w * 32 + fr * 16 + ql][lg * 4]);
#pragma unroll
        for (int fn = 0; fn < 4; fn++) bfr[fn] = ld_frag(&Bs[fn * 16 + ql][lg * 4]);
#pragma unroll
        for (int fr = 0; fr < 2; fr++)
#pragma unroll
            for (int fn = 0; fn < 4; fn++)
                acc[fr][fn] = __builtin_amdgcn_mfma_f32_16x16x32_bf16(af[fr], bfr[fn], acc[fr][fn], 0, 0, 0);
        __syncthreads();
    }

#pragma unroll
    for (int fr = 0; fr < 2; fr++)
#pragma unroll
        for (int fn = 0; fn < 4; fn++) {
            float bj = bias[j0 + fn * 16 + ql];
#pragma unroll
            for (int r = 0; r < 4; r++) {
                int m = row0 + w * 32 + fr * 16 + lg * 4 + r;
                out[(size_t)m * CC + j0 + fn * 16 + ql] = acc[fr][fn][r] + bj;
            }
        }
}

extern "C" void kernel_launch(void* const* d_in, const int* in_sizes, int n_in,
                              void* d_out, int out_size, void* d_ws, size_t ws_size,
                              hipStream_t stream) {
    const float* x    = (const float*)d_in[0];
    const float* sinp = (const float*)d_in[1];
    const float* cosp = (const float*)d_in[2];
    const float* wqkv = (const float*)d_in[3];
    const float* bqkv = (const float*)d_in[4];
    const float* wout = (const float*)d_in[5];
    const float* bout = (const float*)d_in[6];
    float* out = (float*)d_out;
    char* ws = (char*)d_ws;

    unsigned short* xb  = (unsigned short*)(ws);            // 4096x768 bf16
    unsigned short* wqb = (unsigned short*)(ws + 6291456);  // Wt_qkv [2304][768]
    unsigned short* wob = (unsigned short*)(ws + 9830400);  // Wt_out [768][768]
    unsigned short* qws = (unsigned short*)(ws + 11010048);
    unsigned short* kws = (unsigned short*)(ws + 17301504);
    unsigned short* vws = (unsigned short*)(ws + 23592960);
    unsigned short* yws = (unsigned short*)(ws + 29884416);
    if (ws_size < 36175872) return;

    k_cvt<<<dim3(512), dim3(256), 0, stream>>>(x, xb, MM * CC / 4);
    k_cvtT<<<dim3(36, 12), dim3(256), 0, stream>>>(wqkv, wqb, CC, N3);
    k_cvtT<<<dim3(12, 12), dim3(256), 0, stream>>>(wout, wob, CC, CC);
    k_qkv<<<dim3(32, 36), dim3(256), 0, stream>>>(xb, wqb, bqkv, sinp, cosp, qws, kws, vws);
    k_attn<<<dim3(768), dim3(128), 0, stream>>>(qws, kws, vws, yws);
    k_out<<<dim3(32, 12), dim3(256), 0, stream>>>(yws, wob, bout, out);
}

// Round 14
// 135.680 us; speedup vs baseline: 1.3334x; 1.3334x over previous
//
#include <hip/hip_runtime.h>
#include <hip/hip_bf16.h>

#define BB 2
#define NN 2048
#define CC 768
#define HH 12
#define DD 64
#define MM 4096
#define N3 2304

typedef __attribute__((ext_vector_type(8))) short bf16x8;
typedef __attribute__((ext_vector_type(4))) float f32x4;

// 0.125 (1/sqrt(D)) * log2(e) folded into Q so softmax runs in base-2 units
#define QSCALE 0.18033688011112043f

// Q/K/V fragment-contiguous permutation: within each 32-element k-block, the
// element at offset o is stored at position p(o) = ((o&15)>>2)*8 + (o>>4)*4 + (o&3).
// The MFMA A/B-fragment for lane-group lg is then 8 contiguous shorts at
// position lg*8 -> single 16B load (global or LDS).

__device__ __forceinline__ unsigned short f2bf(float f) {
    union { float f; unsigned u; } v; v.f = f;
    unsigned r = v.u + 0x7FFFu + ((v.u >> 16) & 1u);
    return (unsigned short)(r >> 16);
}

// RNE cast — compiler lowers pairs to v_cvt_pk_bf16_f32 (m240: don't hand-write)
__device__ __forceinline__ short f2bf_rn(float f) {
    union { __hip_bfloat16 h; short s; } v;
    v.h = __float2bfloat16(f);
    return v.s;
}

__device__ __forceinline__ float exp2_hw(float x) {
    float r;
    asm("v_exp_f32 %0, %1" : "=v"(r) : "v"(x));
    return r;
}

// loads elements [0..3] and [16..19] from p (bf16 A/B fragment k-pattern)
__device__ __forceinline__ bf16x8 ld_frag(const unsigned short* p) {
    bf16x8 r;
    __builtin_memcpy(&r, p, 8);
    __builtin_memcpy((char*)&r + 8, p + 16, 8);
    return r;
}

// contiguous 16B fragment load (permuted storage)
__device__ __forceinline__ bf16x8 ld_frag16(const unsigned short* p) {
    bf16x8 r;
    __builtin_memcpy(&r, p, 16);
    return r;
}

__global__ void k_cvt(const float* __restrict__ s, unsigned short* __restrict__ d, int n4) {
    int i = blockIdx.x * blockDim.x + threadIdx.x;
    int st = gridDim.x * blockDim.x;
    for (; i < n4; i += st) {
        float4 v = ((const float4*)s)[i];
        ushort4 o;
        o.x = f2bf(v.x); o.y = f2bf(v.y); o.z = f2bf(v.z); o.w = f2bf(v.w);
        ((ushort4*)d)[i] = o;
    }
}

// transpose+convert: src f32 [R][Cc] -> dst bf16 [Cc][R]; grid (Cc/64, R/64)
__global__ void k_cvtT(const float* __restrict__ s, unsigned short* __restrict__ d,
                       int R, int Cc) {
    __shared__ unsigned short t[64][72];
    const int c0 = blockIdx.x * 64, r0 = blockIdx.y * 64;
    const int tr = threadIdx.x >> 4;
    const int tc = (threadIdx.x & 15) * 4;
#pragma unroll
    for (int i = 0; i < 4; i++) {
        int r = tr + i * 16;
        float4 v = *(const float4*)(s + (size_t)(r0 + r) * Cc + c0 + tc);
        t[tc + 0][r] = f2bf(v.x);
        t[tc + 1][r] = f2bf(v.y);
        t[tc + 2][r] = f2bf(v.z);
        t[tc + 3][r] = f2bf(v.w);
    }
    __syncthreads();
    const int wr = threadIdx.x >> 2;
    const int wc = (threadIdx.x & 3) * 16;
    *(uint4*)(d + (size_t)(c0 + wr) * R + r0 + wc)     = *(uint4*)&t[wr][wc];
    *(uint4*)(d + (size_t)(c0 + wr) * R + r0 + wc + 8) = *(uint4*)&t[wr][wc + 8];
}

// ---------------- GEMM1: qkv = x @ W_qkv + b, fused RoPE ----------------
// grid (32, 36), block 256. Tile 128(M) x 64(N), BK=32. Wt is [N3][CC] (transposed).
// Q, K and V outputs all stored with the frag-contiguous 32-block permutation.
__launch_bounds__(256)
__global__ void k_qkv(const unsigned short* __restrict__ xb,
                      const unsigned short* __restrict__ wt,
                      const float* __restrict__ bias,
                      const float* __restrict__ sinp,
                      const float* __restrict__ cosp,
                      unsigned short* __restrict__ qws,
                      unsigned short* __restrict__ kws,
                      unsigned short* __restrict__ vws) {
    __shared__ unsigned short As[128][40];   // [m][k]
    __shared__ unsigned short Bs[64][40];    // [j][k]
    const int tid = threadIdx.x;
    const int lane = tid & 63, w = tid >> 6;
    const int ql = lane & 15, lg = lane >> 4;
    const int row0 = blockIdx.x * 128;
    const int j0 = blockIdx.y * 64;

    f32x4 acc[2][4];
#pragma unroll
    for (int a = 0; a < 2; a++)
#pragma unroll
        for (int b = 0; b < 4; b++) acc[a][b] = f32x4{0.f, 0.f, 0.f, 0.f};

    const int ar = tid >> 1, ac = (tid & 1) * 16;
    const int jr = tid >> 2, kc = (tid & 3) * 8;

    for (int k0 = 0; k0 < CC; k0 += 32) {
        uint4 av0 = *(const uint4*)(xb + (size_t)(row0 + ar) * CC + k0 + ac);
        uint4 av1 = *(const uint4*)(xb + (size_t)(row0 + ar) * CC + k0 + ac + 8);
        uint4 bv  = *(const uint4*)(wt + (size_t)(j0 + jr) * CC + k0 + kc);
        *(uint4*)&As[ar][ac]     = av0;
        *(uint4*)&As[ar][ac + 8] = av1;
        *(uint4*)&Bs[jr][kc]     = bv;
        __syncthreads();

        bf16x8 af[2], bfr[4];
#pragma unroll
        for (int fr = 0; fr < 2; fr++) af[fr] = ld_frag(&As[w * 32 + fr * 16 + ql][lg * 4]);
#pragma unroll
        for (int fn = 0; fn < 4; fn++) bfr[fn] = ld_frag(&Bs[fn * 16 + ql][lg * 4]);
#pragma unroll
        for (int fr = 0; fr < 2; fr++)
#pragma unroll
            for (int fn = 0; fn < 4; fn++)
                acc[fr][fn] = __builtin_amdgcn_mfma_f32_16x16x32_bf16(af[fr], bfr[fn], acc[fr][fn], 0, 0, 0);
        __syncthreads();
    }

    float vals[2][4][4];
#pragma unroll
    for (int fr = 0; fr < 2; fr++)
#pragma unroll
        for (int fn = 0; fn < 4; fn++) {
            float bj = bias[j0 + fn * 16 + ql];
#pragma unroll
            for (int r = 0; r < 4; r++) vals[fr][fn][r] = acc[fr][fn][r] + bj;
        }
    const int t = j0 / CC;
    const int h = (j0 % CC) >> 6;
    if (t < 2) {
        unsigned short* outp = (t == 0) ? qws : kws;
        const float qs = (t == 0) ? QSCALE : 1.0f;
#pragma unroll
        for (int fr = 0; fr < 2; fr++)
#pragma unroll
            for (int r = 0; r < 4; r++) {
                int m = row0 + w * 32 + fr * 16 + lg * 4 + r;
                int b = m >> 11, n = m & (NN - 1);
#pragma unroll
                for (int fn = 0; fn < 4; fn++) {
                    int d = fn * 16 + ql;
                    float cv = cosp[n * DD + d], sv = sinp[n * DD + d];
                    float other = vals[fr][fn ^ 2][r];  // partner at d +/- 32
                    float rv = (vals[fr][fn][r] * cv + ((fn < 2) ? -other : other) * sv) * qs;
                    // Q and K columns both permuted (frag-contiguous)
                    int dcol = (fn >> 1) * 32 + (ql >> 2) * 8 + (fn & 1) * 4 + (ql & 3);
                    outp[((size_t)(b * HH + h) * NN + n) * DD + dcol] = f2bf(rv);
                }
            }
    } else {
#pragma unroll
        for (int fr = 0; fr < 2; fr++)
#pragma unroll
            for (int r = 0; r < 4; r++) {
                int m = row0 + w * 32 + fr * 16 + lg * 4 + r;
                int b = m >> 11, n = m & (NN - 1);
                // V n-columns permuted within 32-blocks: (n&31) = (fr&1)*16+lg*4+r
                int ncol = (n & ~31) + lg * 8 + (fr & 1) * 4 + r;
#pragma unroll
                for (int fn = 0; fn < 4; fn++) {
                    int d = fn * 16 + ql;
                    vws[((size_t)(b * HH + h) * DD + d) * NN + ncol] = f2bf(vals[fr][fn][r]);
                }
            }
    }
}

// ---------------- Attention (flash, S^T / O^T, dbuf, XCD-swizzled) — R6 structure ----------------
// grid 768 (1-D), block 128 (2 waves). Wave owns 32 q; block 64 q; 64-key K/V tiles.
// K/V in LDS with frag-contiguous permutation -> single ds_read_b128 per fragment.
__launch_bounds__(128)
__global__ void k_attn(const unsigned short* __restrict__ qws,
                       const unsigned short* __restrict__ kws,
                       const unsigned short* __restrict__ vws,
                       unsigned short* __restrict__ yws) {
    __shared__ unsigned short Ks[2][64][72];  // [buf][kk][d-permuted]
    __shared__ unsigned short Vs[2][64][72];  // [buf][d][kk-permuted]
    const int tid = threadIdx.x;
    const int lane = tid & 63, w = tid >> 6;
    const int ql = lane & 15, lg = lane >> 4;
    const int d0 = blockIdx.x;
    const int bh = (d0 & 7) + 8 * (d0 >> 8);     // 0..23, 3 heads per XCD class
    const int qb = (d0 >> 3) & 31;               // 0..31
    const int qw = qb * 64 + w * 32;
    const unsigned short* Qp = qws + (size_t)bh * NN * DD;
    const unsigned short* Kp = kws + (size_t)bh * NN * DD;
    const unsigned short* Vp = vws + (size_t)bh * DD * NN;

    // Q fragments hoisted (B-operand of S^T): col q = ql, k = d (pre-scaled, permuted)
    bf16x8 qf[2][2];
#pragma unroll
    for (int fn = 0; fn < 2; fn++)
#pragma unroll
        for (int kb = 0; kb < 2; kb++)
            qf[fn][kb] = ld_frag16(Qp + (size_t)(qw + fn * 16 + ql) * DD + kb * 32 + lg * 8);

    f32x4 oacc[4][2];
#pragma unroll
    for (int a = 0; a < 4; a++)
#pragma unroll
        for (int b = 0; b < 2; b++) oacc[a][b] = f32x4{0.f, 0.f, 0.f, 0.f};
    float mrun[2] = {-1e30f, -1e30f}, lrun[2] = {0.f, 0.f};

    const int srow = tid >> 1;        // 0..63
    const int shalf = (tid & 1) * 32; // 32-short (one k-block) granularity

    // prologue: stage tile 0 (4 uint4 K + 4 uint4 V per thread)
#pragma unroll
    for (int j = 0; j < 4; j++) {
        *(uint4*)&Ks[0][srow][shalf + j * 8] = *(const uint4*)(Kp + (size_t)srow * DD + shalf + j * 8);
        *(uint4*)&Vs[0][srow][shalf + j * 8] = *(const uint4*)(Vp + (size_t)srow * NN + shalf + j * 8);
    }
    __syncthreads();

    const int NT = NN / 64;
    int cur = 0;
    for (int kt = 0; kt < NT; kt++) {
        // issue next tile's global loads early (L2-local after XCD swizzle) [T14]
        uint4 kn[4], vn[4];
        const bool hasn = (kt + 1 < NT);
        if (hasn) {
#pragma unroll
            for (int j = 0; j < 4; j++) {
                kn[j] = *(const uint4*)(Kp + (size_t)((kt + 1) * 64 + srow) * DD + shalf + j * 8);
                vn[j] = *(const uint4*)(Vp + (size_t)srow * NN + (kt + 1) * 64 + shalf + j * 8);
            }
        }
        const unsigned short (*Kc)[72] = Ks[cur];
        const unsigned short (*Vc)[72] = Vs[cur];

        // S^T[kk][q] = sum_d K[kk][d] * Qs[q][d]   (log2 units)
        f32x4 sacc[4][2];
#pragma unroll
        for (int a = 0; a < 4; a++)
#pragma unroll
            for (int b = 0; b < 2; b++) sacc[a][b] = f32x4{0.f, 0.f, 0.f, 0.f};
        __builtin_amdgcn_s_setprio(1);
#pragma unroll
        for (int kb = 0; kb < 2; kb++) {
            bf16x8 kf[4];
#pragma unroll
            for (int fr = 0; fr < 4; fr++)
                kf[fr] = ld_frag16(&Kc[fr * 16 + ql][kb * 32 + lg * 8]);
#pragma unroll
            for (int fr = 0; fr < 4; fr++)
#pragma unroll
                for (int fn = 0; fn < 2; fn++)
                    sacc[fr][fn] = __builtin_amdgcn_mfma_f32_16x16x32_bf16(kf[fr], qf[fn][kb], sacc[fr][fn], 0, 0, 0);
        }
        __builtin_amdgcn_s_setprio(0);

        // online softmax per q-column (col q = fn*16+ql, stats in-lane + shfl over lg)
        bf16x8 pB[2][2];
#pragma unroll
        for (int fn = 0; fn < 2; fn++) {
            float ma = fmaxf(fmaxf(sacc[0][fn][0], sacc[0][fn][1]), fmaxf(sacc[0][fn][2], sacc[0][fn][3]));
            float mb = fmaxf(fmaxf(sacc[1][fn][0], sacc[1][fn][1]), fmaxf(sacc[1][fn][2], sacc[1][fn][3]));
            float mc = fmaxf(fmaxf(sacc[2][fn][0], sacc[2][fn][1]), fmaxf(sacc[2][fn][2], sacc[2][fn][3]));
            float md = fmaxf(fmaxf(sacc[3][fn][0], sacc[3][fn][1]), fmaxf(sacc[3][fn][2], sacc[3][fn][3]));
            float tm = fmaxf(fmaxf(ma, mb), fmaxf(mc, md));
            tm = fmaxf(tm, __shfl_xor(tm, 16));
            tm = fmaxf(tm, __shfl_xor(tm, 32));
            // defer-max: rescale only when running max grows by more than 8 (log2) [T13]
            if (__any(tm > mrun[fn] + 8.0f)) {
                float mn = fmaxf(mrun[fn], tm);
                float scl = exp2_hw(mrun[fn] - mn);
                lrun[fn] *= scl;
#pragma unroll
                for (int db = 0; db < 4; db++) oacc[db][fn] *= scl;
                mrun[fn] = mn;
            }
            float ts = 0.f;
#pragma unroll
            for (int fr = 0; fr < 4; fr++)
#pragma unroll
                for (int r = 0; r < 4; r++) {
                    float p = exp2_hw(sacc[fr][fn][r] - mrun[fn]);
                    sacc[fr][fn][r] = p;
                    ts += p;
                }
            ts += __shfl_xor(ts, 16);
            ts += __shfl_xor(ts, 32);
            lrun[fn] += ts;

            // in-lane repack: S^T C/D frag -> B-operand frags of PV (RNE pk-cvt)
#pragma unroll
            for (int kkb = 0; kkb < 2; kkb++) {
                bf16x8 t8;
#pragma unroll
                for (int e = 0; e < 8; e++)
                    t8[e] = f2bf_rn(sacc[kkb * 2 + (e >> 2)][fn][e & 3]);
                pB[fn][kkb] = t8;
            }
        }

        // O^T[d][q] += sum_kk V^T[d][kk] P^T[kk][q]
        __builtin_amdgcn_s_setprio(1);
#pragma unroll
        for (int db = 0; db < 4; db++) {
            bf16x8 va[2];
#pragma unroll
            for (int kkb = 0; kkb < 2; kkb++)
                va[kkb] = ld_frag16(&Vc[db * 16 + ql][kkb * 32 + lg * 8]);
#pragma unroll
            for (int kkb = 0; kkb < 2; kkb++)
#pragma unroll
                for (int fn = 0; fn < 2; fn++)
                    oacc[db][fn] = __builtin_amdgcn_mfma_f32_16x16x32_bf16(va[kkb], pB[fn][kkb], oacc[db][fn], 0, 0, 0);
        }
        __builtin_amdgcn_s_setprio(0);

        if (hasn) {
            // write next tile into the other buffer (disjoint), single barrier per iter
#pragma unroll
            for (int j = 0; j < 4; j++) {
                *(uint4*)&Ks[cur ^ 1][srow][shalf + j * 8] = kn[j];
                *(uint4*)&Vs[cur ^ 1][srow][shalf + j * 8] = vn[j];
            }
            __syncthreads();
            cur ^= 1;
        }
    }

    // epilogue: O^T frag row = d, col = q; vectorized 8B stores
    const int b = bh / HH, h = bh % HH;
#pragma unroll
    for (int fn = 0; fn < 2; fn++) {
        float inv = 1.0f / lrun[fn];
        int q = qw + fn * 16 + ql;
        unsigned short* yp = yws + (size_t)(b * NN + q) * CC + h * DD + lg * 4;
#pragma unroll
        for (int db = 0; db < 4; db++) {
            ushort4 o;
            o.x = f2bf(oacc[db][fn][0] * inv);
            o.y = f2bf(oacc[db][fn][1] * inv);
            o.z = f2bf(oacc[db][fn][2] * inv);
            o.w = f2bf(oacc[db][fn][3] * inv);
            *(ushort4*)(yp + db * 16) = o;
        }
    }
}

// ---------------- GEMM2: out = y @ W_out + b_out (f32 out) ----------------
// Wot is [CC][CC] transposed. grid (32,12), block 256, tile 128x64.
__launch_bounds__(256)
__global__ void k_out(const unsigned short* __restrict__ yb,
                      const unsigned short* __restrict__ wt,
                      const float* __restrict__ bias,
                      float* __restrict__ out) {
    __shared__ unsigned short As[128][40];
    __shared__ unsigned short Bs[64][40];
    const int tid = threadIdx.x;
    const int lane = tid & 63, w = tid >> 6;
    const int ql = lane & 15, lg = lane >> 4;
    const int row0 = blockIdx.x * 128;
    const int j0 = blockIdx.y * 64;

    f32x4 acc[2][4];
#pragma unroll
    for (int a = 0; a < 2; a++)
#pragma unroll
        for (int b = 0; b < 4; b++) acc[a][b] = f32x4{0.f, 0.f, 0.f, 0.f};

    const int ar = tid >> 1, ac = (tid & 1) * 16;
    const int jr = tid >> 2, kc = (tid & 3) * 8;

    for (int k0 = 0; k0 < CC; k0 += 32) {
        uint4 av0 = *(const uint4*)(yb + (size_t)(row0 + ar) * CC + k0 + ac);
        uint4 av1 = *(const uint4*)(yb + (size_t)(row0 + ar) * CC + k0 + ac + 8);
        uint4 bv  = *(const uint4*)(wt + (size_t)(j0 + jr) * CC + k0 + kc);
        *(uint4*)&As[ar][ac]     = av0;
        *(uint4*)&As[ar][ac + 8] = av1;
        *(uint4*)&Bs[jr][kc]     = bv;
        __syncthreads();

        bf16x8 af[2], bfr[4];
#pragma unroll
        for (int fr = 0; fr < 2; fr++) af[fr] = ld_frag(&As[w * 32 + fr * 16 + ql][lg * 4]);
#pragma unroll
        for (int fn = 0; fn < 4; fn++) bfr[fn] = ld_frag(&Bs[fn * 16 + ql][lg * 4]);
#pragma unroll
        for (int fr = 0; fr < 2; fr++)
#pragma unroll
            for (int fn = 0; fn < 4; fn++)
                acc[fr][fn] = __builtin_amdgcn_mfma_f32_16x16x32_bf16(af[fr], bfr[fn], acc[fr][fn], 0, 0, 0);
        __syncthreads();
    }

#pragma unroll
    for (int fr = 0; fr < 2; fr++)
#pragma unroll
        for (int fn = 0; fn < 4; fn++) {
            float bj = bias[j0 + fn * 16 + ql];
#pragma unroll
            for (int r = 0; r < 4; r++) {
                int m = row0 + w * 32 + fr * 16 + lg * 4 + r;
                out[(size_t)m * CC + j0 + fn * 16 + ql] = acc[fr][fn][r] + bj;
            }
        }
}

extern "C" void kernel_launch(void* const* d_in, const int* in_sizes, int n_in,
                              void* d_out, int out_size, void* d_ws, size_t ws_size,
                              hipStream_t stream) {
    const float* x    = (const float*)d_in[0];
    const float* sinp = (const float*)d_in[1];
    const float* cosp = (const float*)d_in[2];
    const float* wqkv = (const float*)d_in[3];
    const float* bqkv = (const float*)d_in[4];
    const float* wout = (const float*)d_in[5];
    const float* bout = (const float*)d_in[6];
    float* out = (float*)d_out;
    char* ws = (char*)d_ws;

    unsigned short* xb  = (unsigned short*)(ws);            // 4096x768 bf16
    unsigned short* wqb = (unsigned short*)(ws + 6291456);  // Wt_qkv [2304][768]
    unsigned short* wob = (unsigned short*)(ws + 9830400);  // Wt_out [768][768]
    unsigned short* qws = (unsigned short*)(ws + 11010048);
    unsigned short* kws = (unsigned short*)(ws + 17301504);
    unsigned short* vws = (unsigned short*)(ws + 23592960);
    unsigned short* yws = (unsigned short*)(ws + 29884416);
    if (ws_size < 36175872) return;

    k_cvt<<<dim3(512), dim3(256), 0, stream>>>(x, xb, MM * CC / 4);
    k_cvtT<<<dim3(36, 12), dim3(256), 0, stream>>>(wqkv, wqb, CC, N3);
    k_cvtT<<<dim3(12, 12), dim3(256), 0, stream>>>(wout, wob, CC, CC);
    k_qkv<<<dim3(32, 36), dim3(256), 0, stream>>>(xb, wqb, bqkv, sinp, cosp, qws, kws, vws);
    k_attn<<<dim3(768), dim3(128), 0, stream>>>(qws, kws, vws, yws);
    k_out<<<dim3(32, 12), dim3(256), 0, stream>>>(yws, wob, bout, out);
}